// Round 3
// baseline (85.430 us; speedup 1.0000x reference)
//
#include <hip/hip_runtime.h>

// SKANLinear: y[b,o] = sum_{i=0}^{IN} weight[o,i] * sin(w[o,i] * x_ext[b,i])
// x_ext[b,IN] = 1.0. B=2048, IN=256, OUT=256. f32.
//
// R7: polynomial sin on the FULL-RATE VALU. Evidence: R4 (SMEM coeffs),
// R5 (LDS coeffs), R6 (VGPR coeffs) -- structurally disjoint delivery
// schemes -- all measured ~36us kernel. The shared term is 134.7M
// v_sin_f32; implied wave64 v_sin throughput ~40 cyc (trans pipe is the
// serializing resource, NOT memory/issue). Fix: sin(2*pi*f) with
// branch-free exact reduction r = f - rndne(f) in [-0.5,0.5] and an odd
// deg-9 Chebyshev poly (max err ~3e-5 abs; tolerance is 0.0625):
//   f=wc*x | rndne | sub | q=r*r | 4 FMA Horner | u=g*r | acc=fma(u,P,acc)
// = 10 full-rate ops = 20 cyc/wave64-elem vs ~42 cyc of v_sin alone.
// Rest identical to R6: lane=(b_sub,i_sub), coeffs resident in VGPRs
// (wc pre-scaled by 1/2pi), x transposed through LDS (80B slots),
// DPP row_ror 16-lane reduce. ~17us VALU-bound floor.

#define IN_DIM 256
#define OUT_DIM 256
#define LDW 257
#define INV_2PI 0.15915494309189535f
#define BTILE 32
#define NBG (BTILE / 4)     // 8 groups of 4 b-rows per block
#define SLOT 20             // floats per 16-float x slot (80 B: bank-spread)

// sin(2*pi*r) ~= r * P(r^2), r in [-0.5, 0.5].  Chebyshev-truncated series
// (coeffs = 2*sum Bessel J_k(pi) * T_k expansion, y=2r):
#define PA0  6.283124f
#define PA1 -41.332608f
#define PA2  81.373184f
#define PA3 -74.481664f
#define PA4  32.768f

__device__ __forceinline__ float sinpoly_acc(float wc, float g, float x, float acc) {
    const float f = wc * x;                    // revolutions
    const float r = f - __builtin_rintf(f);    // v_rndne_f32, exact reduction
    const float q = r * r;
    float p = fmaf(q, PA4, PA3);
    p = fmaf(q, p, PA2);
    p = fmaf(q, p, PA1);
    p = fmaf(q, p, PA0);
    return fmaf(g * r, p, acc);
}

template <int CTRL>
__device__ __forceinline__ float ror_add(float v) {
    // v += rotate-within-16-lane-row(v, CTRL); after ror 1,2,4,8 every lane
    // in the row holds the full 16-lane sum. VALU pipe (no LDS).
    const int m = __builtin_amdgcn_update_dpp(0, __float_as_int(v),
                                              CTRL, 0xf, 0xf, true);
    return v + __int_as_float(m);
}

__global__ __launch_bounds__(256, 4)
void skan_kernel(const float* __restrict__ x,      // [2048][256]
                 const float* __restrict__ weight, // [256][257]
                 const float* __restrict__ wfreq,  // [256][257]
                 float* __restrict__ y)            // [2048][256]
{
    __shared__ __align__(16) float lxT[2][4 * 16 * SLOT];   // 2 x 5120 B

    const int t    = threadIdx.x;
    const int l    = t & 63;
    const int wv   = t >> 6;        // wave id 0..3
    const int isub = l & 15;        // i-run index (16 contiguous i's each)
    const int bsub = l >> 4;        // b row within 4-b group

    const int obase = (blockIdx.x & 31) * 8;       // 32 o-tiles of 8
    const int b0    = (blockIdx.x >> 5) * BTILE;   // 64 b-tiles of 32
    const int o0    = obase + wv * 2;              // wave owns o0, o0+1

    // ---- coefficients -> VGPRs, once; w scaled by 1/2pi here ----
    float wc0[16], gc0[16], wc1[16], gc1[16];
    {
        const float* wp = wfreq  + o0 * LDW + isub * 16;
        const float* gp = weight + o0 * LDW + isub * 16;
#pragma unroll
        for (int j = 0; j < 16; ++j) {
            wc0[j] = wp[j]       * INV_2PI;
            gc0[j] = gp[j];
            wc1[j] = wp[LDW + j] * INV_2PI;
            gc1[j] = gp[LDW + j];
        }
    }
    // bias column i=256 (x_ext = 1): wave-uniform, added after reduction
    const float bias0 = sinpoly_acc(wfreq[o0 * LDW + IN_DIM] * INV_2PI,
                                    weight[o0 * LDW + IN_DIM], 1.0f, 0.0f);
    const float bias1 = sinpoly_acc(wfreq[(o0 + 1) * LDW + IN_DIM] * INV_2PI,
                                    weight[(o0 + 1) * LDW + IN_DIM], 1.0f, 0.0f);

    // ---- x staging maps ----
    // read: thread t covers row (b0 + bg*4 + t>>6), floats (t&63)*4 .. +3
    //       (64 threads x 16 B = one contiguous 1 KB row per wave: coalesced)
    // write: those 4 floats land contiguously in slot (srow, i_sub=(t&63)>>2)
    //       at float offset ((t&3)*4)  -> one ds_write_b128, banks ~2-way
    const int    srow = t >> 6;
    const float* xsrc = x + (b0 + srow) * IN_DIM + (t & 63) * 4;
    const int    dsto = (srow * 16 + ((t & 63) >> 2)) * SLOT + (t & 3) * 4;
    const int    rdo  = (bsub * 16 + isub) * SLOT;   // compute-read slot base

    // prologue: stage group 0
    {
        const float4 v = *(const float4*)xsrc;
        *(float4*)&lxT[0][dsto] = v;
    }

    for (int bg = 0; bg < NBG; ++bg) {
        __syncthreads();               // stage(bg) visible to all waves
        const int cur = bg & 1;

        // my 16 x-values (contiguous i-run), 4x ds_read_b128, balanced banks
        float xv[16];
        *(float4*)&xv[0]  = *(const float4*)&lxT[cur][rdo + 0];
        *(float4*)&xv[4]  = *(const float4*)&lxT[cur][rdo + 4];
        *(float4*)&xv[8]  = *(const float4*)&lxT[cur][rdo + 8];
        *(float4*)&xv[12] = *(const float4*)&lxT[cur][rdo + 12];

        // issue next group's global load early; HBM/L2 latency hides under VALU
        float4 nx;
        if (bg + 1 < NBG) nx = *(const float4*)(xsrc + (bg + 1) * 4 * IN_DIM);

        // ---- pure-VALU core: all operands in registers, no trans ops ----
        float a0 = 0.f, a1 = 0.f;
#pragma unroll
        for (int j = 0; j < 16; ++j) {
            const float xj = xv[j];
            a0 = sinpoly_acc(wc0[j], gc0[j], xj, a0);
            a1 = sinpoly_acc(wc1[j], gc1[j], xj, a1);
        }

        // write next group into the other buffer (its last readers finished
        // before this iteration's barrier)
        if (bg + 1 < NBG) *(float4*)&lxT[cur ^ 1][dsto] = nx;

        // 16-lane i_sub reduction on the VALU pipe (DPP), per o
        a0 = ror_add<0x121>(a0); a0 = ror_add<0x122>(a0);
        a0 = ror_add<0x124>(a0); a0 = ror_add<0x128>(a0);
        a1 = ror_add<0x121>(a1); a1 = ror_add<0x122>(a1);
        a1 = ror_add<0x124>(a1); a1 = ror_add<0x128>(a1);

        // every lane in a 16-row now holds the full sum; lanes isub<2 store
        if (isub < 2) {
            const float out = (isub == 0) ? a0 + bias0 : a1 + bias1;
            y[(b0 + bg * 4 + bsub) * OUT_DIM + o0 + isub] = out;
        }
    }
}

extern "C" void kernel_launch(void* const* d_in, const int* in_sizes, int n_in,
                              void* d_out, int out_size, void* d_ws, size_t ws_size,
                              hipStream_t stream) {
    const float* x      = (const float*)d_in[0];
    const float* weight = (const float*)d_in[1];
    const float* wfreq  = (const float*)d_in[2];
    float* y            = (float*)d_out;

    const int B = in_sizes[0] / IN_DIM;                 // 2048
    const int grid = (B / BTILE) * (OUT_DIM / 8);       // 64 * 32 = 2048

    skan_kernel<<<grid, 256, 0, stream>>>(x, weight, wfreq, y);
}

// Round 4
// 81.998 us; speedup vs baseline: 1.0419x; 1.0419x over previous
//
#include <hip/hip_runtime.h>

// SKANLinear: y[b,o] = sum_{i=0}^{IN} weight[o,i] * sin(w[o,i] * x_ext[b,i])
// x_ext[b,IN] = 1.0. B=2048, IN=256, OUT=256. f32.
//
// R8: pure-register dataflow, ZERO LDS / ZERO barriers.
// Evidence so far: R6(v_sin)->R7(poly) delta matched marginal instruction
// count (+8us for +7 slots/elem) => issue-bound at the margin, v_sin is
// cheap. skan never appears in top-5 (fills are 40us) => kernel < 40us and
// dur_us carries a fixed non-kernel component. This round removes every
// remaining non-issue cost from the kernel: lane=(b_sub[0..4),i_sub[0..16)),
// coefficients (2 o x 16 i x {w,g} = 64 VGPRs) loaded once; x read DIRECTLY
// from global per 4-b group (4x global_load_dwordx4 per lane, 16B-aligned,
// L2/L3-resident; 4x wave redundancy ~ 7us of 34TB/s L2 BW) with a
// register prefetch of the next group hiding VMEM latency under the 32-sin
// block. No __syncthreads anywhere -> no inter-wave convoys. DPP row_ror
// 16-lane reduce on the VALU pipe. ~120 VGPR, 4 waves/SIMD.
// Floor: ~900 instr/wave * 2-3.4k cyc => ~11-14us kernel.

#define IN_DIM 256
#define OUT_DIM 256
#define LDW 257
#define INV_2PI 0.15915494309189535f
#define BTILE 32
#define NBG (BTILE / 4)     // 8 groups of 4 b-rows per block

template <int CTRL>
__device__ __forceinline__ float ror_add(float v) {
    // v += rotate-within-16-lane-row(v, CTRL); ror 1,2,4,8 -> every lane in
    // the 16-lane row holds the full row sum. VALU pipe (no LDS).
    const int m = __builtin_amdgcn_update_dpp(0, __float_as_int(v),
                                              CTRL, 0xf, 0xf, true);
    return v + __int_as_float(m);
}

__global__ __launch_bounds__(256, 4)
void skan_kernel(const float* __restrict__ x,      // [2048][256]
                 const float* __restrict__ weight, // [256][257]
                 const float* __restrict__ wfreq,  // [256][257]
                 float* __restrict__ y)            // [2048][256]
{
    const int t    = threadIdx.x;
    const int l    = t & 63;
    const int wv   = t >> 6;        // wave id 0..3
    const int isub = l & 15;        // i-run index (16 contiguous i's each)
    const int bsub = l >> 4;        // b row within 4-b group

    const int obase = (blockIdx.x & 31) * 8;       // 32 o-tiles of 8
    const int b0    = (blockIdx.x >> 5) * BTILE;   // 64 b-tiles of 32
    const int o0    = obase + wv * 2;              // wave owns o0, o0+1

    // ---- coefficients -> VGPRs, once; w pre-scaled by 1/2pi (v_sin takes
    // revolutions). Scalar loads: once per kernel, L2/L3-warm, negligible.
    float wc0[16], gc0[16], wc1[16], gc1[16];
    {
        const float* wp = wfreq  + o0 * LDW + isub * 16;
        const float* gp = weight + o0 * LDW + isub * 16;
#pragma unroll
        for (int j = 0; j < 16; ++j) {
            wc0[j] = wp[j]       * INV_2PI;
            gc0[j] = gp[j];
            wc1[j] = wp[LDW + j] * INV_2PI;
            gc1[j] = gp[LDW + j];
        }
    }
    // bias column i=256 (x_ext = 1): wave-uniform, added after reduction
    const float bias0 = weight[o0 * LDW + IN_DIM] *
                        __builtin_amdgcn_sinf(wfreq[o0 * LDW + IN_DIM] * INV_2PI);
    const float bias1 = weight[(o0 + 1) * LDW + IN_DIM] *
                        __builtin_amdgcn_sinf(wfreq[(o0 + 1) * LDW + IN_DIM] * INV_2PI);

    // lane's x window: row (b0 + bsub), cols isub*16 .. +15  (16B-aligned)
    const float* xlane = x + (b0 + bsub) * IN_DIM + isub * 16;

    float xv[16], nx[16];
    // prologue: load group 0
    *(float4*)&xv[0]  = *(const float4*)(xlane + 0);
    *(float4*)&xv[4]  = *(const float4*)(xlane + 4);
    *(float4*)&xv[8]  = *(const float4*)(xlane + 8);
    *(float4*)&xv[12] = *(const float4*)(xlane + 12);

#pragma unroll
    for (int bg = 0; bg < NBG; ++bg) {
        // prefetch next 4-b group; latency hides under the 32-sin block
        if (bg + 1 < NBG) {
            const float* xp = xlane + (bg + 1) * 4 * IN_DIM;
            *(float4*)&nx[0]  = *(const float4*)(xp + 0);
            *(float4*)&nx[4]  = *(const float4*)(xp + 4);
            *(float4*)&nx[8]  = *(const float4*)(xp + 8);
            *(float4*)&nx[12] = *(const float4*)(xp + 12);
        }

        // ---- core: all operands in registers; mul + v_sin + fma ----
        float a0 = 0.f, a1 = 0.f;
#pragma unroll
        for (int j = 0; j < 16; ++j) {
            const float xj = xv[j];
            a0 = fmaf(gc0[j], __builtin_amdgcn_sinf(wc0[j] * xj), a0);
            a1 = fmaf(gc1[j], __builtin_amdgcn_sinf(wc1[j] * xj), a1);
        }

        // 16-lane i_sub reduction on the VALU pipe (DPP), per o
        a0 = ror_add<0x121>(a0); a0 = ror_add<0x122>(a0);
        a0 = ror_add<0x124>(a0); a0 = ror_add<0x128>(a0);
        a1 = ror_add<0x121>(a1); a1 = ror_add<0x122>(a1);
        a1 = ror_add<0x124>(a1); a1 = ror_add<0x128>(a1);

        // every lane in a 16-row holds the full sum; lanes isub<2 store
        if (isub < 2) {
            const float out = (isub == 0) ? a0 + bias0 : a1 + bias1;
            y[(b0 + bg * 4 + bsub) * OUT_DIM + o0 + isub] = out;
        }

        // rotate prefetch buffer in (renamed away under full unroll)
#pragma unroll
        for (int j = 0; j < 16; ++j) xv[j] = nx[j];
    }
}

extern "C" void kernel_launch(void* const* d_in, const int* in_sizes, int n_in,
                              void* d_out, int out_size, void* d_ws, size_t ws_size,
                              hipStream_t stream) {
    const float* x      = (const float*)d_in[0];
    const float* weight = (const float*)d_in[1];
    const float* wfreq  = (const float*)d_in[2];
    float* y            = (float*)d_out;

    const int B = in_sizes[0] / IN_DIM;                 // 2048
    const int grid = (B / BTILE) * (OUT_DIM / 8);       // 64 * 32 = 2048

    skan_kernel<<<grid, 256, 0, stream>>>(x, weight, wfreq, y);
}